// Round 11
// baseline (237.009 us; speedup 1.0000x reference)
//
#include <hip/hip_runtime.h>
#include <math.h>

// Problem constants (fixed by reference): B=4, S=2048, D=512, H=8, R=8, dk=64
#define B_ 4
#define S_ 2048
#define D_ 512
#define H_ 8
#define R_ 8
#define DK_ 64
#define EPB   (2*R_*S_)         // 32768 edges per (b,h)
#define ELLCAP 64               // max in-degree slots; Poisson(15) tail ~2e-8

typedef __attribute__((ext_vector_type(8))) short bf16x8;
typedef __attribute__((ext_vector_type(8))) unsigned short ushort8_t;
typedef __attribute__((ext_vector_type(4))) float f32x4;

#define AS1q const __attribute__((address_space(1)))
#define AS3q __attribute__((address_space(3)))

__device__ inline unsigned short f2bf(float f) {
    unsigned u = __builtin_bit_cast(unsigned, f);
    u += 0x7fffu + ((u >> 16) & 1u);   // RNE (no NaN inputs here)
    return (unsigned short)(u >> 16);
}

// ---------------- prep: W converts only (q/k/v/rel stay fp32) ---------------
__global__ __launch_bounds__(256) void prep_w(
    const float* __restrict__ Wq, const float* __restrict__ Wk,
    const float* __restrict__ Wv, const float* __restrict__ Wo,
    unsigned short* __restrict__ wqb, unsigned short* __restrict__ wkb,
    unsigned short* __restrict__ wvb, unsigned short* __restrict__ wob)
{
    int bid = blockIdx.x;                  // 1024 blocks
    int z = bid >> 8;                      // 0..3
    const float* x = (z == 0) ? Wq : (z == 1) ? Wk : (z == 2) ? Wv : Wo;
    unsigned short* y = (z == 0) ? wqb : (z == 1) ? wkb : (z == 2) ? wvb : wob;
    size_t i = ((size_t)(bid & 255) * 256 + threadIdx.x) * 4;
    float4 v = *(const float4*)&x[i];
    *(ushort4*)&y[i] = make_ushort4(f2bf(v.x), f2bf(v.y), f2bf(v.z), f2bf(v.w));
}

// ---------------- QKV GEMM: fp32 A inline-cvt, bf16 W via global_load_lds ---
// C fp32 [B,H,S,dk] = A[m,k] * W[n,k] + bias. 128x128 tile, BK=64, 4 waves.
// 1-D grid, XCD m-grouping: xcd=bi&7 owns m-tiles [xcd*8, xcd*8+8); n fastest
// -> A m-strip HBM-fetched once, 3 more times from that XCD's L2.
__global__ __launch_bounds__(256) void gemm_qkv(
    const float* __restrict__ A0, const float* __restrict__ A1,
    const float* __restrict__ A2,
    const unsigned short* __restrict__ W0, const unsigned short* __restrict__ W1,
    const unsigned short* __restrict__ W2,
    const float* __restrict__ bi0, const float* __restrict__ bi1, const float* __restrict__ bi2,
    float* __restrict__ C0, float* __restrict__ C1, float* __restrict__ C2)
{
    __shared__ unsigned short As[128 * 64];
    __shared__ unsigned short Bs[128 * 64];
    const int bi  = blockIdx.x;           // 768
    const int xcd = bi & 7;
    const int r   = bi >> 3;              // 0..95
    const int z   = r >> 5;               // 0..2
    const int rr  = r & 31;
    const int m0  = (xcd * 8 + (rr >> 2)) * 128;
    const int n0  = (rr & 3) * 128;

    const float* A          = (z == 0) ? A0 : (z == 1) ? A1 : A2;
    const unsigned short* W = (z == 0) ? W0 : (z == 1) ? W1 : W2;
    const float* bias       = (z == 0) ? bi0 : (z == 1) ? bi1 : bi2;
    float* C                = (z == 0) ? C0 : (z == 1) ? C1 : C2;

    const int t    = threadIdx.x;
    const int lane = t & 63;
    const int w    = t >> 6;
    const int wm   = w >> 1, wn = w & 1;
    const int lr    = lane >> 3;           // row within 8-row stage chunk
    const int cglob = (lane & 7) ^ lr;     // swizzled global source chunk

    f32x4 acc[4][4] = {};

    for (int kk = 0; kk < D_; kk += 64) {
        // A: fp32 load + convert + ds_write_b128 (same LDS pattern as
        // global_load_lds: contiguous lane*16B per 8-row chunk, conflict-free)
        #pragma unroll
        for (int i = 0; i < 4; ++i) {
            int rowl = w * 32 + i * 8;
            const float* ga = A + (size_t)(m0 + rowl + lr) * D_ + kk + cglob * 8;
            float4 a0 = *(const float4*)ga;
            float4 a1 = *(const float4*)(ga + 4);
            ushort8_t c;
            c[0] = f2bf(a0.x); c[1] = f2bf(a0.y); c[2] = f2bf(a0.z); c[3] = f2bf(a0.w);
            c[4] = f2bf(a1.x); c[5] = f2bf(a1.y); c[6] = f2bf(a1.z); c[7] = f2bf(a1.w);
            *(ushort8_t*)&As[(rowl + lr) * 64 + (lane & 7) * 8] = c;
            // W: bf16, direct-to-LDS DMA
            const unsigned short* gb =
                W + (size_t)(n0 + rowl + lr) * D_ + kk + cglob * 8;
            __builtin_amdgcn_global_load_lds((AS1q unsigned*)gb,
                (AS3q unsigned*)(Bs + rowl * 64), 16, 0, 0);
        }
        __syncthreads();

        #pragma unroll
        for (int ks = 0; ks < 64; ks += 32) {
            const int c0 = ks >> 3;
            bf16x8 af[4], bfr[4];
            #pragma unroll
            for (int mi = 0; mi < 4; ++mi) {
                int row = wm * 64 + mi * 16 + (lane & 15);
                int cp  = (c0 + (lane >> 4)) ^ (lane & 7);
                af[mi] = *(const bf16x8*)&As[row * 64 + cp * 8];
            }
            #pragma unroll
            for (int nj = 0; nj < 4; ++nj) {
                int row = wn * 64 + nj * 16 + (lane & 15);
                int cp  = (c0 + (lane >> 4)) ^ (lane & 7);
                bfr[nj] = *(const bf16x8*)&Bs[row * 64 + cp * 8];
            }
            #pragma unroll
            for (int mi = 0; mi < 4; ++mi)
                #pragma unroll
                for (int nj = 0; nj < 4; ++nj)
                    acc[mi][nj] = __builtin_amdgcn_mfma_f32_16x16x32_bf16(af[mi], bfr[nj], acc[mi][nj], 0, 0, 0);
        }
        __syncthreads();
    }

    // epilogue: fp32 [B,H,S,dk]
    #pragma unroll
    for (int mi = 0; mi < 4; ++mi) {
        #pragma unroll
        for (int nj = 0; nj < 4; ++nj) {
            #pragma unroll
            for (int rg = 0; rg < 4; ++rg) {
                int m = m0 + wm * 64 + mi * 16 + (lane >> 4) * 4 + rg;
                int n = n0 + wn * 64 + nj * 16 + (lane & 15);
                float val = acc[mi][nj][rg] + bias[n];
                int b = m >> 11, s = m & (S_ - 1);
                int h = n >> 6,  d = n & 63;
                C[((((size_t)b * H_ + h) * S_ + s) << 6) + d] = val;
            }
        }
    }
}

// ---------------- output GEMM: bf16 A (bhsd) -> fp32 row-major --------------
// 128x64 tile; 1-D grid with XCD m-grouping (8 n-tiles per m-strip on one XCD).
__global__ __launch_bounds__(256) void gemm_out(
    const unsigned short* __restrict__ A, const unsigned short* __restrict__ W,
    const float* __restrict__ bias, float* __restrict__ Cf)
{
    __shared__ unsigned short As[128 * 64];
    __shared__ unsigned short Bs[64 * 64];
    const int bi  = blockIdx.x;           // 512
    const int xcd = bi & 7;
    const int r   = bi >> 3;              // 0..63
    const int m0  = (xcd * 8 + (r >> 3)) * 128;
    const int n0  = (r & 7) * 64;

    const int t    = threadIdx.x;
    const int lane = t & 63;
    const int w    = t >> 6;
    const int wm   = w >> 1, wn = w & 1;
    const int lr    = lane >> 3;
    const int cglob = (lane & 7) ^ lr;

    f32x4 acc[4][2] = {};

    for (int kk = 0; kk < D_; kk += 64) {
        #pragma unroll
        for (int i = 0; i < 4; ++i) {
            int rowl = w * 32 + i * 8;
            int m = m0 + rowl + lr;
            int b = m >> 11, s = m & (S_ - 1), h = kk >> 6;
            const unsigned short* ga =
                A + ((((size_t)b * H_ + h) * S_ + s) << 6) + cglob * 8;
            __builtin_amdgcn_global_load_lds((AS1q unsigned*)ga,
                (AS3q unsigned*)(As + rowl * 64), 16, 0, 0);
        }
        #pragma unroll
        for (int i = 0; i < 2; ++i) {
            int rowl = w * 16 + i * 8;
            const unsigned short* gb =
                W + (size_t)(n0 + rowl + lr) * D_ + kk + cglob * 8;
            __builtin_amdgcn_global_load_lds((AS1q unsigned*)gb,
                (AS3q unsigned*)(Bs + rowl * 64), 16, 0, 0);
        }
        __syncthreads();

        #pragma unroll
        for (int ks = 0; ks < 64; ks += 32) {
            const int c0 = ks >> 3;
            bf16x8 af[4], bfr[2];
            #pragma unroll
            for (int mi = 0; mi < 4; ++mi) {
                int row = wm * 64 + mi * 16 + (lane & 15);
                int cp  = (c0 + (lane >> 4)) ^ (lane & 7);
                af[mi] = *(const bf16x8*)&As[row * 64 + cp * 8];
            }
            #pragma unroll
            for (int nj = 0; nj < 2; ++nj) {
                int row = wn * 32 + nj * 16 + (lane & 15);
                int cp  = (c0 + (lane >> 4)) ^ (lane & 7);
                bfr[nj] = *(const bf16x8*)&Bs[row * 64 + cp * 8];
            }
            #pragma unroll
            for (int mi = 0; mi < 4; ++mi)
                #pragma unroll
                for (int nj = 0; nj < 2; ++nj)
                    acc[mi][nj] = __builtin_amdgcn_mfma_f32_16x16x32_bf16(af[mi], bfr[nj], acc[mi][nj], 0, 0, 0);
        }
        __syncthreads();
    }

    #pragma unroll
    for (int mi = 0; mi < 4; ++mi) {
        #pragma unroll
        for (int nj = 0; nj < 2; ++nj) {
            #pragma unroll
            for (int rg = 0; rg < 4; ++rg) {
                int m = m0 + wm * 64 + mi * 16 + (lane >> 4) * 4 + rg;
                int n = n0 + wn * 32 + nj * 16 + (lane & 15);
                Cf[(size_t)m * D_ + n] = acc[mi][nj][rg] + bias[n];
            }
        }
    }
}

// ---------------- fused ELL-build + score+softmax+aggregate (fp32 data) -----
// One block per (bh, 128-dst window); LDS ELL never hits global. fp32 q/k/v
// and ORIGINAL fp32 rel_* -> zero dtype conversions in the edge loop.
__global__ __launch_bounds__(1024) void attn_fused(
    const float* __restrict__ q, const float* __restrict__ k_,
    const float* __restrict__ v_,
    const float* __restrict__ rel_q, const float* __restrict__ rel_k,
    const float* __restrict__ rel_v,
    const int* __restrict__ start_nodes, const int* __restrict__ end_nodes,
    unsigned short* __restrict__ attn)
{
    __shared__ unsigned short ell[128 * ELLCAP];   // 16 KB
    __shared__ int cnt[128];
    const int bi  = blockIdx.x;          // 512 blocks
    const int xcd = bi & 7;
    const int loc = bi >> 3;             // 0..63
    const int bh  = xcd * 4 + (loc >> 4);
    const int dlo = (loc & 15) << 7;     // 128-dst window base
    const int t   = threadIdx.x;

    if (t < 128) cnt[t] = 0;
    __syncthreads();

    // ---- scan phase ----
    const int base_idx = bh * (R_ * S_);
    for (int f = t; f < EPB; f += 1024) {   // 32 iterations
        int r2 = f >> 11;
        if (r2 == 0) continue;              // first-S flat entries masked
        int s = f & (S_ - 1);
        int idx = base_idx + (r2 & 7) * S_ + s;
        int sn = start_nodes[idx];
        if (sn == -1) continue;             // padded edge
        int en = end_nodes[idx];
        int dst = (r2 < R_) ? en : sn;
        unsigned rel = (unsigned)(dst - dlo);
        if (rel < 128u) {
            int ki = (r2 < R_) ? sn : en;
            int pos = atomicAdd(&cnt[rel], 1);
            if (pos < ELLCAP)
                ell[(rel << 6) + pos] = (unsigned short)((r2 << 11) | ki);
        }
    }
    __syncthreads();

    // ---- gather phase ----
    const int w    = t >> 6;
    const int lane = t & 63;
    const int grp  = lane >> 3;          // edge slot within group-of-8
    const int sub  = lane & 7;           // dk chunk (8 elems)
    const int h    = bh & 7;
    const size_t node_base = ((size_t)bh << 11);

    for (int dd = 0; dd < 8; ++dd) {
        int dl  = dd * 16 + w;           // 0..127
        int dst = dlo + dl;

        float qv[8];
        *(float4*)&qv[0] = *(const float4*)&q[((node_base + dst) << 6) + sub * 8];
        *(float4*)&qv[4] = *(const float4*)&q[((node_base + dst) << 6) + sub * 8 + 4];

        int n = cnt[dl];
        if (n > ELLCAP) n = ELLCAP;
        int d_all = (int)ell[(dl << 6) + lane];

        float den = 0.f;
        float o[8] = {};
        #pragma unroll 2
        for (int j = 0; j < n; j += 8) {
            int slot = j + grp;
            int d = __shfl(d_all, slot);
            bool valid = slot < n;
            int ki = d & (S_ - 1);
            int r2 = (d >> 11) & 15;
            size_t koff = ((node_base + ki) << 6) + sub * 8;
            int roff = (((h << 4) + r2) << 6) + sub * 8;
            float kv[8], rqv[8], rkv[8], vv[8], rvv[8];
            *(float4*)&kv[0]  = *(const float4*)&k_[koff];
            *(float4*)&kv[4]  = *(const float4*)&k_[koff + 4];
            *(float4*)&rqv[0] = *(const float4*)&rel_q[roff];
            *(float4*)&rqv[4] = *(const float4*)&rel_q[roff + 4];
            *(float4*)&rkv[0] = *(const float4*)&rel_k[roff];
            *(float4*)&rkv[4] = *(const float4*)&rel_k[roff + 4];
            float p = 0.f;
            #pragma unroll
            for (int i = 0; i < 8; ++i)
                p = fmaf(kv[i], qv[i] + rqv[i], fmaf(qv[i], rkv[i], p));
            p += __shfl_xor(p, 1);
            p += __shfl_xor(p, 2);
            p += __shfl_xor(p, 4);
            float sf = valid ? __expf(p * (1.0f / 24.0f)) : 0.f;   // 3*sqrt(64)=24
            *(float4*)&vv[0]  = *(const float4*)&v_[koff];
            *(float4*)&vv[4]  = *(const float4*)&v_[koff + 4];
            *(float4*)&rvv[0] = *(const float4*)&rel_v[roff];
            *(float4*)&rvv[4] = *(const float4*)&rel_v[roff + 4];
            den += sf;
            #pragma unroll
            for (int i = 0; i < 8; ++i)
                o[i] = fmaf(sf, vv[i] + rvv[i], o[i]);
        }
        den += __shfl_xor(den, 8); den += __shfl_xor(den, 16); den += __shfl_xor(den, 32);
        #pragma unroll
        for (int i = 0; i < 8; ++i) {
            o[i] += __shfl_xor(o[i], 8);
            o[i] += __shfl_xor(o[i], 16);
            o[i] += __shfl_xor(o[i], 32);
        }
        if (grp == 0) {
            float inv = (den > 0.f) ? 1.0f / den : 0.f;
            ushort8_t rs;
            #pragma unroll
            for (int i = 0; i < 8; ++i) rs[i] = f2bf(o[i] * inv);
            *(ushort8_t*)&attn[((node_base + dst) << 6) + sub * 8] = rs;
        }
    }
}

extern "C" void kernel_launch(void* const* d_in, const int* in_sizes, int n_in,
                              void* d_out, int out_size, void* d_ws, size_t ws_size,
                              hipStream_t stream) {
    const float* query = (const float*)d_in[0];
    const float* key   = (const float*)d_in[1];
    const float* value = (const float*)d_in[2];
    const int* start_nodes = (const int*)d_in[3];
    const int* end_nodes   = (const int*)d_in[4];
    const float* rel_q = (const float*)d_in[5];
    const float* rel_k = (const float*)d_in[6];
    const float* rel_v = (const float*)d_in[7];
    const float* Wq = (const float*)d_in[8];
    const float* bq = (const float*)d_in[9];
    const float* Wk = (const float*)d_in[10];
    const float* bk = (const float*)d_in[11];
    const float* Wv = (const float*)d_in[12];
    const float* bv = (const float*)d_in[13];
    const float* Wo = (const float*)d_in[14];
    const float* bo = (const float*)d_in[15];
    float* out = (float*)d_out;

    const size_t NQ = (size_t)B_ * H_ * S_ * DK_;   // 4,194,304
    const size_t NW = (size_t)D_ * D_;              // 262,144
    // ws layout: q,k,v fp32 (48 MB) + attn bf16 (8 MB) + W bf16 (2 MB)
    float* qf = (float*)d_ws;
    float* kf = qf + NQ;
    float* vf = kf + NQ;
    unsigned short* attn = (unsigned short*)(vf + NQ);
    unsigned short* wqb  = attn + NQ;
    unsigned short* wkb  = wqb + NW;
    unsigned short* wvb  = wkb + NW;
    unsigned short* wob  = wvb + NW;

    // 1) W converts only
    prep_w<<<1024, 256, 0, stream>>>(Wq, Wk, Wv, Wo, wqb, wkb, wvb, wob);

    // 2) fused QKV projection (fp32 A inline-cvt, fp32 C, XCD m-grouping)
    gemm_qkv<<<768, 256, 0, stream>>>(query, key, value, wqb, wkb, wvb,
                                      bq, bk, bv, qf, kf, vf);

    // 3) fused ELL-build + attention (fp32 q/k/v, original fp32 rel_*)
    attn_fused<<<512, 1024, 0, stream>>>(qf, kf, vf, rel_q, rel_k, rel_v,
                                         start_nodes, end_nodes, attn);

    // 4) output projection (bf16 attn -> fp32 out, XCD m-grouping)
    gemm_out<<<512, 256, 0, stream>>>(attn, wob, bo, out);
}

// Round 12
// 223.515 us; speedup vs baseline: 1.0604x; 1.0604x over previous
//
#include <hip/hip_runtime.h>
#include <math.h>

// Problem constants (fixed by reference): B=4, S=2048, D=512, H=8, R=8, dk=64
#define B_ 4
#define S_ 2048
#define D_ 512
#define H_ 8
#define R_ 8
#define DK_ 64
#define EPB   (2*R_*S_)         // 32768 edges per (b,h)
#define ELLCAP 64               // max in-degree slots; Poisson(15) tail ~2e-8

typedef __attribute__((ext_vector_type(8))) short bf16x8;
typedef __attribute__((ext_vector_type(8))) unsigned short ushort8_t;
typedef __attribute__((ext_vector_type(4))) float f32x4;

#define AS1q const __attribute__((address_space(1)))
#define AS3q __attribute__((address_space(3)))

__device__ inline unsigned short f2bf(float f) {
    unsigned u = __builtin_bit_cast(unsigned, f);
    u += 0x7fffu + ((u >> 16) & 1u);   // RNE (no NaN inputs here)
    return (unsigned short)(u >> 16);
}
__device__ inline float bf2f(unsigned short u) {
    return __builtin_bit_cast(float, ((unsigned)u) << 16);
}

// ---------------- prep: qkv converts + W fragment-swizzle + rel converts ----
// blocks 0..12287: q/k/v cvt; 12288..12799: W -> W' fragment layout;
// 12800..12823: rel cvt.
// W' layout: W'[((ng*16 + kc)*64 + lane)*8 + j] = W[(ng*16 + (lane&15))*512
//            + kc*32 + (lane>>4)*8 + j]  -> a wave's B-fragment load is one
//            coalesced 1 KB global_load_dwordx4 at block base + lane*16.
__global__ __launch_bounds__(256) void prep(
    const float* __restrict__ query, const float* __restrict__ key,
    const float* __restrict__ value,
    const float* __restrict__ Wq, const float* __restrict__ Wk,
    const float* __restrict__ Wv, const float* __restrict__ Wo,
    const float* __restrict__ rel_q, const float* __restrict__ rel_k,
    const float* __restrict__ rel_v,
    unsigned short* __restrict__ qc, unsigned short* __restrict__ kc_,
    unsigned short* __restrict__ vc,
    unsigned short* __restrict__ wqp, unsigned short* __restrict__ wkp,
    unsigned short* __restrict__ wvp, unsigned short* __restrict__ wop,
    unsigned short* __restrict__ rqb, unsigned short* __restrict__ rkb,
    unsigned short* __restrict__ rvb)
{
    int bid = blockIdx.x;
    int t = threadIdx.x;
    if (bid < 12288) {
        int z = bid >> 12;                 // 0..2
        const float* x = (z == 0) ? query : (z == 1) ? key : value;
        unsigned short* y = (z == 0) ? qc : (z == 1) ? kc_ : vc;
        size_t i = ((size_t)(bid & 4095) * 256 + t) * 4;
        float4 v = *(const float4*)&x[i];
        *(ushort4*)&y[i] = make_ushort4(f2bf(v.x), f2bf(v.y), f2bf(v.z), f2bf(v.w));
    } else if (bid < 12800) {
        int r = bid - 12288;               // 0..511
        int z = r >> 7;                    // 0..3
        const float* x = (z == 0) ? Wq : (z == 1) ? Wk : (z == 2) ? Wv : Wo;
        unsigned short* y = (z == 0) ? wqp : (z == 1) ? wkp : (z == 2) ? wvp : wop;
        int fi = (r & 127) * 256 + t;      // 0..32767 fragment-slot index
        int ng   = fi >> 10;
        int kc   = (fi >> 6) & 15;
        int lane = fi & 63;
        const float* src = x + (size_t)(ng * 16 + (lane & 15)) * D_
                             + kc * 32 + (lane >> 4) * 8;
        float4 a0 = *(const float4*)src;
        float4 a1 = *(const float4*)(src + 4);
        ushort8_t c;
        c[0] = f2bf(a0.x); c[1] = f2bf(a0.y); c[2] = f2bf(a0.z); c[3] = f2bf(a0.w);
        c[4] = f2bf(a1.x); c[5] = f2bf(a1.y); c[6] = f2bf(a1.z); c[7] = f2bf(a1.w);
        *(ushort8_t*)&y[(size_t)fi * 8] = c;
    } else {
        int rr = bid - 12800;              // 0..23
        int z = rr >> 3;                   // 0..2
        const float* x = (z == 0) ? rel_q : (z == 1) ? rel_k : rel_v;
        unsigned short* y = (z == 0) ? rqb : (z == 1) ? rkb : rvb;
        size_t i = ((size_t)(rr & 7) * 256 + t) * 4;
        float4 v = *(const float4*)&x[i];
        *(ushort4*)&y[i] = make_ushort4(f2bf(v.x), f2bf(v.y), f2bf(v.z), f2bf(v.w));
    }
}

// ---------------- QKV GEMM: bf16 A via global_load_lds, W' direct-to-reg ----
// C bf16 [B,H,S,dk] = A[m,k]*W[n,k] + bias. 128x128 tile, BK=64, 4 waves 2x2.
// W fragments load straight from L2 (coalesced via W' layout) -> no Bs LDS,
// no barrier dependency for W; compiler prefetches W across the As barrier.
// 1-D grid, XCD m-grouping: A m-strip HBM-fetched once, reused from L2.
__global__ __launch_bounds__(256) void gemm_qkv(
    const unsigned short* __restrict__ A0, const unsigned short* __restrict__ A1,
    const unsigned short* __restrict__ A2,
    const unsigned short* __restrict__ W0, const unsigned short* __restrict__ W1,
    const unsigned short* __restrict__ W2,
    const float* __restrict__ bi0, const float* __restrict__ bi1, const float* __restrict__ bi2,
    unsigned short* __restrict__ C0, unsigned short* __restrict__ C1,
    unsigned short* __restrict__ C2)
{
    __shared__ unsigned short As[128 * 64];
    const int bi  = blockIdx.x;           // 768
    const int xcd = bi & 7;
    const int r   = bi >> 3;              // 0..95
    const int z   = r >> 5;               // 0..2
    const int rr  = r & 31;
    const int m0  = (xcd * 8 + (rr >> 2)) * 128;
    const int n0  = (rr & 3) * 128;

    const unsigned short* A = (z == 0) ? A0 : (z == 1) ? A1 : A2;
    const unsigned short* W = (z == 0) ? W0 : (z == 1) ? W1 : W2;
    const float* bias       = (z == 0) ? bi0 : (z == 1) ? bi1 : bi2;
    unsigned short* C       = (z == 0) ? C0 : (z == 1) ? C1 : C2;

    const int t    = threadIdx.x;
    const int lane = t & 63;
    const int w    = t >> 6;
    const int wm   = w >> 1, wn = w & 1;
    const int lr    = lane >> 3;           // row within 8-row stage chunk
    const int cglob = (lane & 7) ^ lr;     // swizzled global source chunk

    f32x4 acc[4][4] = {};

    for (int kk = 0; kk < D_; kk += 64) {
        #pragma unroll
        for (int i = 0; i < 4; ++i) {
            int rowl = w * 32 + i * 8;
            const unsigned short* ga =
                A + (size_t)(m0 + rowl + lr) * D_ + kk + cglob * 8;
            __builtin_amdgcn_global_load_lds((AS1q unsigned*)ga,
                (AS3q unsigned*)(As + rowl * 64), 16, 0, 0);
        }
        __syncthreads();

        #pragma unroll
        for (int ks = 0; ks < 64; ks += 32) {
            const int c0 = ks >> 3;
            const int kc = (kk + ks) >> 5;
            bf16x8 af[4], bfr[4];
            #pragma unroll
            for (int mi = 0; mi < 4; ++mi) {
                int row = wm * 64 + mi * 16 + (lane & 15);
                int cp  = (c0 + (lane >> 4)) ^ (lane & 7);
                af[mi] = *(const bf16x8*)&As[row * 64 + cp * 8];
            }
            #pragma unroll
            for (int nj = 0; nj < 4; ++nj) {
                int ng = (n0 >> 4) + wn * 4 + nj;
                bfr[nj] = *(const bf16x8*)&W[(size_t)((ng * 16 + kc) << 6) * 8 + lane * 8];
            }
            #pragma unroll
            for (int mi = 0; mi < 4; ++mi)
                #pragma unroll
                for (int nj = 0; nj < 4; ++nj)
                    acc[mi][nj] = __builtin_amdgcn_mfma_f32_16x16x32_bf16(af[mi], bfr[nj], acc[mi][nj], 0, 0, 0);
        }
        __syncthreads();
    }

    // epilogue: bf16 [B,H,S,dk]
    #pragma unroll
    for (int mi = 0; mi < 4; ++mi) {
        #pragma unroll
        for (int nj = 0; nj < 4; ++nj) {
            #pragma unroll
            for (int rg = 0; rg < 4; ++rg) {
                int m = m0 + wm * 64 + mi * 16 + (lane >> 4) * 4 + rg;
                int n = n0 + wn * 64 + nj * 16 + (lane & 15);
                float val = acc[mi][nj][rg] + bias[n];
                int b = m >> 11, s = m & (S_ - 1);
                int h = n >> 6,  d = n & 63;
                C[((((size_t)b * H_ + h) * S_ + s) << 6) + d] = f2bf(val);
            }
        }
    }
}

// ---------------- output GEMM: bf16 A (bhsd), W' direct-reg, fp32 out -------
__global__ __launch_bounds__(256) void gemm_out(
    const unsigned short* __restrict__ A, const unsigned short* __restrict__ W,
    const float* __restrict__ bias, float* __restrict__ Cf)
{
    __shared__ unsigned short As[128 * 64];
    const int bi  = blockIdx.x;           // 512
    const int xcd = bi & 7;
    const int r   = bi >> 3;              // 0..63
    const int m0  = (xcd * 8 + (r >> 3)) * 128;
    const int n0  = (r & 7) * 64;

    const int t    = threadIdx.x;
    const int lane = t & 63;
    const int w    = t >> 6;
    const int wm   = w >> 1, wn = w & 1;
    const int lr    = lane >> 3;
    const int cglob = (lane & 7) ^ lr;

    f32x4 acc[4][2] = {};

    for (int kk = 0; kk < D_; kk += 64) {
        #pragma unroll
        for (int i = 0; i < 4; ++i) {
            int rowl = w * 32 + i * 8;
            int m = m0 + rowl + lr;
            int b = m >> 11, s = m & (S_ - 1), h = kk >> 6;
            const unsigned short* ga =
                A + ((((size_t)b * H_ + h) * S_ + s) << 6) + cglob * 8;
            __builtin_amdgcn_global_load_lds((AS1q unsigned*)ga,
                (AS3q unsigned*)(As + rowl * 64), 16, 0, 0);
        }
        __syncthreads();

        #pragma unroll
        for (int ks = 0; ks < 64; ks += 32) {
            const int c0 = ks >> 3;
            const int kc = (kk + ks) >> 5;
            bf16x8 af[4], bfr[2];
            #pragma unroll
            for (int mi = 0; mi < 4; ++mi) {
                int row = wm * 64 + mi * 16 + (lane & 15);
                int cp  = (c0 + (lane >> 4)) ^ (lane & 7);
                af[mi] = *(const bf16x8*)&As[row * 64 + cp * 8];
            }
            #pragma unroll
            for (int nj = 0; nj < 2; ++nj) {
                int ng = (n0 >> 4) + wn * 2 + nj;
                bfr[nj] = *(const bf16x8*)&W[(size_t)((ng * 16 + kc) << 6) * 8 + lane * 8];
            }
            #pragma unroll
            for (int mi = 0; mi < 4; ++mi)
                #pragma unroll
                for (int nj = 0; nj < 2; ++nj)
                    acc[mi][nj] = __builtin_amdgcn_mfma_f32_16x16x32_bf16(af[mi], bfr[nj], acc[mi][nj], 0, 0, 0);
        }
        __syncthreads();
    }

    #pragma unroll
    for (int mi = 0; mi < 4; ++mi) {
        #pragma unroll
        for (int nj = 0; nj < 2; ++nj) {
            #pragma unroll
            for (int rg = 0; rg < 4; ++rg) {
                int m = m0 + wm * 64 + mi * 16 + (lane >> 4) * 4 + rg;
                int n = n0 + wn * 32 + nj * 16 + (lane & 15);
                Cf[(size_t)m * D_ + n] = acc[mi][nj][rg] + bias[n];
            }
        }
    }
}

// ---------------- fused ELL-build + score+softmax+aggregate (R10 — best) ----
__global__ __launch_bounds__(1024) void attn_fused(
    const unsigned short* __restrict__ q, const unsigned short* __restrict__ k_,
    const unsigned short* __restrict__ v_,
    const unsigned short* __restrict__ rel_q, const unsigned short* __restrict__ rel_k,
    const unsigned short* __restrict__ rel_v,
    const int* __restrict__ start_nodes, const int* __restrict__ end_nodes,
    unsigned short* __restrict__ attn)
{
    __shared__ unsigned short ell[128 * ELLCAP];   // 16 KB
    __shared__ int cnt[128];
    const int bi  = blockIdx.x;          // 512 blocks
    const int xcd = bi & 7;
    const int loc = bi >> 3;             // 0..63
    const int bh  = xcd * 4 + (loc >> 4);
    const int dlo = (loc & 15) << 7;     // 128-dst window base
    const int t   = threadIdx.x;

    if (t < 128) cnt[t] = 0;
    __syncthreads();

    // ---- scan phase ----
    const int base_idx = bh * (R_ * S_);
    for (int f = t; f < EPB; f += 1024) {   // 32 iterations
        int r2 = f >> 11;
        if (r2 == 0) continue;              // first-S flat entries masked
        int s = f & (S_ - 1);
        int idx = base_idx + (r2 & 7) * S_ + s;
        int sn = start_nodes[idx];
        if (sn == -1) continue;             // padded edge
        int en = end_nodes[idx];
        int dst = (r2 < R_) ? en : sn;
        unsigned rel = (unsigned)(dst - dlo);
        if (rel < 128u) {
            int ki = (r2 < R_) ? sn : en;
            int pos = atomicAdd(&cnt[rel], 1);
            if (pos < ELLCAP)
                ell[(rel << 6) + pos] = (unsigned short)((r2 << 11) | ki);
        }
    }
    __syncthreads();

    // ---- gather phase ----
    const int w    = t >> 6;
    const int lane = t & 63;
    const int grp  = lane >> 3;          // edge slot within group-of-8
    const int sub  = lane & 7;           // dk chunk (8 elems)
    const int h    = bh & 7;
    const size_t node_base = ((size_t)bh << 11);

    for (int dd = 0; dd < 8; ++dd) {
        int dl  = dd * 16 + w;           // 0..127
        int dst = dlo + dl;

        ushort8_t q8 = *(const ushort8_t*)&q[((node_base + dst) << 6) + sub * 8];
        float qv[8];
        #pragma unroll
        for (int i = 0; i < 8; ++i) qv[i] = bf2f(q8[i]);

        int n = cnt[dl];
        if (n > ELLCAP) n = ELLCAP;
        int d_all = (int)ell[(dl << 6) + lane];

        float den = 0.f;
        float o[8] = {};
        #pragma unroll 2
        for (int j = 0; j < n; j += 8) {
            int slot = j + grp;
            int d = __shfl(d_all, slot);
            bool valid = slot < n;
            int ki = d & (S_ - 1);
            int r2 = (d >> 11) & 15;
            ushort8_t k8  = *(const ushort8_t*)&k_  [((node_base + ki) << 6) + sub * 8];
            ushort8_t rk8 = *(const ushort8_t*)&rel_k[(((h << 4) + r2) << 6) + sub * 8];
            ushort8_t rq8 = *(const ushort8_t*)&rel_q[(((h << 4) + r2) << 6) + sub * 8];
            float p = 0.f;
            #pragma unroll
            for (int i = 0; i < 8; ++i)
                p = fmaf(bf2f(k8[i]), qv[i] + bf2f(rq8[i]),
                         fmaf(qv[i], bf2f(rk8[i]), p));
            p += __shfl_xor(p, 1);
            p += __shfl_xor(p, 2);
            p += __shfl_xor(p, 4);
            float sf = valid ? __expf(p * (1.0f / 24.0f)) : 0.f;   // 3*sqrt(64)=24
            ushort8_t v8  = *(const ushort8_t*)&v_  [((node_base + ki) << 6) + sub * 8];
            ushort8_t rv8 = *(const ushort8_t*)&rel_v[(((h << 4) + r2) << 6) + sub * 8];
            den += sf;
            #pragma unroll
            for (int i = 0; i < 8; ++i)
                o[i] = fmaf(sf, bf2f(v8[i]) + bf2f(rv8[i]), o[i]);
        }
        den += __shfl_xor(den, 8); den += __shfl_xor(den, 16); den += __shfl_xor(den, 32);
        #pragma unroll
        for (int i = 0; i < 8; ++i) {
            o[i] += __shfl_xor(o[i], 8);
            o[i] += __shfl_xor(o[i], 16);
            o[i] += __shfl_xor(o[i], 32);
        }
        if (grp == 0) {
            float inv = (den > 0.f) ? 1.0f / den : 0.f;
            ushort8_t rs;
            #pragma unroll
            for (int i = 0; i < 8; ++i) rs[i] = f2bf(o[i] * inv);
            *(ushort8_t*)&attn[((node_base + dst) << 6) + sub * 8] = rs;
        }
    }
}

extern "C" void kernel_launch(void* const* d_in, const int* in_sizes, int n_in,
                              void* d_out, int out_size, void* d_ws, size_t ws_size,
                              hipStream_t stream) {
    const float* query = (const float*)d_in[0];
    const float* key   = (const float*)d_in[1];
    const float* value = (const float*)d_in[2];
    const int* start_nodes = (const int*)d_in[3];
    const int* end_nodes   = (const int*)d_in[4];
    const float* rel_q = (const float*)d_in[5];
    const float* rel_k = (const float*)d_in[6];
    const float* rel_v = (const float*)d_in[7];
    const float* Wq = (const float*)d_in[8];
    const float* bq = (const float*)d_in[9];
    const float* Wk = (const float*)d_in[10];
    const float* bk = (const float*)d_in[11];
    const float* Wv = (const float*)d_in[12];
    const float* bv = (const float*)d_in[13];
    const float* Wo = (const float*)d_in[14];
    const float* bo = (const float*)d_in[15];
    float* out = (float*)d_out;

    const size_t NQ = (size_t)B_ * H_ * S_ * DK_;   // 4,194,304
    const size_t NW = (size_t)D_ * D_;              // 262,144
    const size_t NR = (size_t)H_ * 2 * R_ * DK_;    // 8,192
    unsigned short* p = (unsigned short*)d_ws;
    unsigned short* qc = p;            p += NQ;   // converted inputs (bf16)
    unsigned short* kc = p;            p += NQ;
    unsigned short* vc = p;            p += NQ;
    unsigned short* q  = p;            p += NQ;   // projections bf16 [B,H,S,dk]
    unsigned short* k  = p;            p += NQ;
    unsigned short* v  = p;            p += NQ;
    unsigned short* attn = p;          p += NQ;
    unsigned short* wqp = p;           p += NW;   // W' fragment layouts
    unsigned short* wkp = p;           p += NW;
    unsigned short* wvp = p;           p += NW;
    unsigned short* wop = p;           p += NW;
    unsigned short* rqb = p;           p += NR;
    unsigned short* rkb = p;           p += NR;
    unsigned short* rvb = p;           p += NR;

    // 1) fused converts + W fragment-swizzle (one dispatch)
    prep<<<12824, 256, 0, stream>>>(query, key, value, Wq, Wk, Wv, Wo,
                                    rel_q, rel_k, rel_v,
                                    qc, kc, vc, wqp, wkp, wvp, wop,
                                    rqb, rkb, rvb);

    // 2) fused QKV projection (W direct-to-reg, As-only LDS)
    gemm_qkv<<<768, 256, 0, stream>>>(qc, kc, vc, wqp, wkp, wvp,
                                      bq, bk, bv, q, k, v);

    // 3) fused ELL-build + attention (R10-proven bf16 version)
    attn_fused<<<512, 1024, 0, stream>>>(q, k, v, rqb, rkb, rvb,
                                         start_nodes, end_nodes, attn);

    // 4) output projection (bf16 attn -> fp32 out)
    gemm_out<<<512, 256, 0, stream>>>(attn, wop, bo, out);
}